// Round 11
// baseline (174.734 us; speedup 1.0000x reference)
//
#include <hip/hip_runtime.h>
#include <hip/hip_bf16.h>

#define BB  8
#define CC  128
#define LXX 4096
#define LYY 1024
#define HH  4
#define DHH 32

typedef __attribute__((ext_vector_type(8))) short bf16x8;
typedef __attribute__((ext_vector_type(4))) float f32x4;

static __device__ __forceinline__ unsigned short f2bf(float f) {
    __hip_bfloat16 h = __float2bfloat16(f);
    return *reinterpret_cast<unsigned short*>(&h);
}

static __device__ __forceinline__ bf16x8 pack8(const float* f) {
    bf16x8 r;
#pragma unroll
    for (int i = 0; i < 8; ++i) {
        __hip_bfloat16 h = __float2bfloat16(f[i]);
        r[i] = *reinterpret_cast<short*>(&h);
    }
    return r;
}

// ================= merged MFMA projection (+fused conv for x) — unchanged from R3 =================
__global__ __launch_bounds__(256) void proj_all_kernel(
    const float* __restrict__ x, const float* __restrict__ y,
    const float* __restrict__ ipw, const float* __restrict__ ipb,
    const float* __restrict__ c1w, const float* __restrict__ c1b,
    const float* __restrict__ c2w, const float* __restrict__ c2b,
    unsigned short* __restrict__ Qb, unsigned short* __restrict__ Kb,
    float* __restrict__ localS, float qscale)
{
    int tid  = threadIdx.x;
    int wv   = tid >> 6;
    int lane = tid & 63;
    int n16  = lane & 15;
    int quad = lane >> 4;

    int blk = blockIdx.x;
    bool isX = (blk < 512);
    const float* src; const float* wrow; const float* bias;
    unsigned short* dst; int L, bi, l0; float scale;
    if (isX) {
        bi = blk >> 6; l0 = (blk & 63) * 64;
        src = x + (size_t)bi * CC * LXX; L = LXX;
        wrow = ipw; bias = ipb; dst = Qb; scale = qscale;
    } else {
        int b2 = blk - 512;
        bi = b2 >> 4; l0 = (b2 & 15) * 64;
        src = y + (size_t)bi * CC * LYY; L = LYY;
        wrow = ipw + CC * CC; bias = ipb + CC; dst = Kb; scale = 1.0f;
    }
    int lw = l0 + wv * 16;
    int myl = lw + n16;

    bf16x8 bfr[4];
#pragma unroll
    for (int kk = 0; kk < 4; ++kk) {
        float t[8];
        const float* p = src + (size_t)(kk * 32 + quad * 8) * L + myl;
#pragma unroll
        for (int j = 0; j < 8; ++j) t[j] = p[(size_t)j * L];
        bfr[kk] = pack8(t);
    }

    const f32x4 fzero = {0.f, 0.f, 0.f, 0.f};

#pragma unroll 1
    for (int m = 0; m < 8; ++m) {
        int mc = m * 16;
        f32x4 acc = fzero;
#pragma unroll
        for (int kk = 0; kk < 4; ++kk) {
            const float* wp = wrow + (size_t)(mc + n16) * CC + kk * 32 + quad * 8;
            float t[8];
            *(float4*)(t) = *(const float4*)(wp);
            *(float4*)(t + 4) = *(const float4*)(wp + 4);
            bf16x8 afr = pack8(t);
            acc = __builtin_amdgcn_mfma_f32_16x16x32_bf16(afr, bfr[kk], acc, 0, 0, 0);
        }
        int h = mc >> 5, d0 = (mc & 31) + quad * 4;
        ushort4 u;
        float4 bq = *(const float4*)(bias + mc + quad * 4);
        u.x = f2bf((acc[0] + bq.x) * scale);
        u.y = f2bf((acc[1] + bq.y) * scale);
        u.z = f2bf((acc[2] + bq.z) * scale);
        u.w = f2bf((acc[3] + bq.w) * scale);
        *(ushort4*)(dst + (((size_t)(bi * HH + h) * L) + myl) * DHH + d0) = u;
    }

    if (isX) {
        float p = 0.f;
#pragma unroll
        for (int m2 = 0; m2 < 2; ++m2) {
            f32x4 hacc = fzero;
#pragma unroll
            for (int kk = 0; kk < 4; ++kk) {
                const float* wp = c1w + (size_t)(m2 * 16 + n16) * CC + kk * 32 + quad * 8;
                float t[8];
                *(float4*)(t) = *(const float4*)(wp);
                *(float4*)(t + 4) = *(const float4*)(wp + 4);
                bf16x8 afr = pack8(t);
                hacc = __builtin_amdgcn_mfma_f32_16x16x32_bf16(afr, bfr[kk], hacc, 0, 0, 0);
            }
#pragma unroll
            for (int r = 0; r < 4; ++r) {
                int o = m2 * 16 + quad * 4 + r;
                p = fmaf(c2w[o], fmaxf(hacc[r] + c1b[o], 0.0f), p);
            }
        }
        p += __shfl_xor(p, 16, 64);
        p += __shfl_xor(p, 32, 64);
        if (quad == 0) {
            float s = p + c2b[0];
            localS[(size_t)bi * LXX + myl] = 1.0f / (1.0f + __expf(-s));
        }
    }
}

// ================= fused attention v7: R8 structure, trimmed reg pressure =================
// grid (LX/32, B), 256 thr = 4 waves; wave w owns key quarter [w*256, +256).
// Two-phase block-local softmax (2 barriers). unroll 1 on the t-loops halves
// in-flight MFMA outputs (AGPR) vs R8; launch_bounds(256,5) targets 5 waves/EU
// (~102-reg cap) without R9's collapse.
__global__ __launch_bounds__(256, 5) void attn_fused_kernel(
    const unsigned short* __restrict__ Qh, const unsigned short* __restrict__ Kh,
    const float* __restrict__ localS,
    const float* __restrict__ gw, const float* __restrict__ gb,
    float* __restrict__ out)
{
    int tid = threadIdx.x;
    int w = tid >> 6;           // key quarter 0..3
    int lane = tid & 63;
    int n16 = lane & 15;
    int quad = lane >> 4;
    int bi = blockIdx.y;
    int q0 = blockIdx.x * 32;

    __shared__ float dlds[4][2][HH][16];   // [w][qt][h][row]
    __shared__ float mlds[4][2][16];       // [w][qt][row]

    bf16x8 afr[2][HH];
#pragma unroll
    for (int qt = 0; qt < 2; ++qt)
#pragma unroll
        for (int h = 0; h < HH; ++h)
            afr[qt][h] = *(const bf16x8*)(Qh +
                (((size_t)bi * HH + h) * LXX + q0 + qt * 16 + n16) * DHH + quad * 8);

    const unsigned short* Kbase = Kh + (((size_t)bi * HH) * LYY + w * 256 + n16) * DHH + quad * 8;

    const f32x4 fzero = {0.f, 0.f, 0.f, 0.f};

    // ---- phase 1: denominators over this wave's 256 keys ----
    f32x4 den[2][HH];
#pragma unroll
    for (int qt = 0; qt < 2; ++qt)
#pragma unroll
        for (int h = 0; h < HH; ++h) den[qt][h] = fzero;

#pragma unroll 1
    for (int t = 0; t < 16; ++t) {
        bf16x8 bfr[HH];
#pragma unroll
        for (int h = 0; h < HH; ++h)
            bfr[h] = *(const bf16x8*)(Kbase + ((size_t)h * LYY + t * 16) * DHH);
#pragma unroll
        for (int h = 0; h < HH; ++h) {
            f32x4 s0 = __builtin_amdgcn_mfma_f32_16x16x32_bf16(afr[0][h], bfr[h], fzero, 0, 0, 0);
            f32x4 s1 = __builtin_amdgcn_mfma_f32_16x16x32_bf16(afr[1][h], bfr[h], fzero, 0, 0, 0);
#pragma unroll
            for (int r = 0; r < 4; ++r) {
                den[0][h][r] += __builtin_amdgcn_exp2f(s0[r]);
                den[1][h][r] += __builtin_amdgcn_exp2f(s1[r]);
            }
        }
    }
#pragma unroll
    for (int off = 1; off < 16; off <<= 1)
#pragma unroll
        for (int qt = 0; qt < 2; ++qt)
#pragma unroll
            for (int h = 0; h < HH; ++h)
#pragma unroll
                for (int r = 0; r < 4; ++r)
                    den[qt][h][r] += __shfl_xor(den[qt][h][r], off, 64);
    if (n16 == 0) {
#pragma unroll
        for (int qt = 0; qt < 2; ++qt)
#pragma unroll
            for (int h = 0; h < HH; ++h)
#pragma unroll
                for (int r = 0; r < 4; ++r) dlds[w][qt][h][quad * 4 + r] = den[qt][h][r];
    }
    __syncthreads();

    // c = -log2(total den); broadcast LDS reads
    f32x4 cc[2][HH];
#pragma unroll
    for (int qt = 0; qt < 2; ++qt)
#pragma unroll
        for (int h = 0; h < HH; ++h)
#pragma unroll
            for (int r = 0; r < 4; ++r) {
                int row = quad * 4 + r;
                float d = dlds[0][qt][h][row] + dlds[1][qt][h][row] +
                          dlds[2][qt][h][row] + dlds[3][qt][h][row];
                cc[qt][h][r] = -__builtin_amdgcn_logf(d);
            }

    // ---- phase 2: f(k) = sum_h exp2(s + c_h); running max over keys ----
    f32x4 vm0 = fzero, vm1 = fzero;    // f(k) > 0, so 0 is a valid -inf
#pragma unroll 1
    for (int t = 0; t < 16; ++t) {
        bf16x8 bfr[HH];
#pragma unroll
        for (int h = 0; h < HH; ++h)
            bfr[h] = *(const bf16x8*)(Kbase + ((size_t)h * LYY + t * 16) * DHH);
        f32x4 f0 = fzero, f1 = fzero;
#pragma unroll
        for (int h = 0; h < HH; ++h) {
            f32x4 s0 = __builtin_amdgcn_mfma_f32_16x16x32_bf16(afr[0][h], bfr[h], cc[0][h], 0, 0, 0);
            f32x4 s1 = __builtin_amdgcn_mfma_f32_16x16x32_bf16(afr[1][h], bfr[h], cc[1][h], 0, 0, 0);
#pragma unroll
            for (int r = 0; r < 4; ++r) {
                f0[r] += __builtin_amdgcn_exp2f(s0[r]);
                f1[r] += __builtin_amdgcn_exp2f(s1[r]);
            }
        }
#pragma unroll
        for (int r = 0; r < 4; ++r) {
            vm0[r] = fmaxf(vm0[r], f0[r]);
            vm1[r] = fmaxf(vm1[r], f1[r]);
        }
    }
#pragma unroll
    for (int off = 1; off < 16; off <<= 1)
#pragma unroll
        for (int r = 0; r < 4; ++r) {
            vm0[r] = fmaxf(vm0[r], __shfl_xor(vm0[r], off, 64));
            vm1[r] = fmaxf(vm1[r], __shfl_xor(vm1[r], off, 64));
        }
    if (n16 == 0) {
#pragma unroll
        for (int r = 0; r < 4; ++r) {
            mlds[w][0][quad * 4 + r] = vm0[r];
            mlds[w][1][quad * 4 + r] = vm1[r];
        }
    }
    __syncthreads();
    if (tid < 32) {
        int qq = tid >> 4;
        int row = tid & 15;
        float m = fmaxf(fmaxf(mlds[0][qq][row], mlds[1][qq][row]),
                        fmaxf(mlds[2][qq][row], mlds[3][qq][row]));
        float cs = 0.25f * m;
        int orow = q0 + qq * 16 + row;
        float ls = localS[(size_t)bi * LXX + orow];
        float z = gw[0] * cs + gw[1] * ls + gb[0];
        float alpha = 1.0f / (1.0f + __expf(-z));
        out[(size_t)bi * LXX + orow] = alpha * cs + (1.0f - alpha) * ls;
    }
}

extern "C" void kernel_launch(void* const* d_in, const int* in_sizes, int n_in,
                              void* d_out, int out_size, void* d_ws, size_t ws_size,
                              hipStream_t stream) {
    const float* x   = (const float*)d_in[0];
    const float* y   = (const float*)d_in[1];
    const float* ipw = (const float*)d_in[2];
    const float* ipb = (const float*)d_in[3];
    const float* c1w = (const float*)d_in[4];
    const float* c1b = (const float*)d_in[5];
    const float* c2w = (const float*)d_in[6];
    const float* c2b = (const float*)d_in[7];
    const float* gw  = (const float*)d_in[8];
    const float* gb  = (const float*)d_in[9];
    float* out = (float*)d_out;

    float* localS = (float*)d_ws;                                // 32768 f32
    unsigned short* Qb = (unsigned short*)(localS + 32768);      // B*H*LX*DH bf16
    unsigned short* Kb = Qb + (size_t)BB * HH * LXX * DHH;       // B*H*LY*DH bf16

    // 1/sqrt(32) * log2(e): exp2-domain softmax, folded into Q only
    const float qscale = 0.17677669529663687f * 1.4426950408889634f;

    hipLaunchKernelGGL(proj_all_kernel, dim3(640), dim3(256), 0, stream,
                       x, y, ipw, ipb, c1w, c1b, c2w, c2b, Qb, Kb, localS, qscale);
    hipLaunchKernelGGL(attn_fused_kernel, dim3(LXX / 32, BB), dim3(256), 0, stream,
                       Qb, Kb, localS, gw, gb, out);
}

// Round 12
// 146.546 us; speedup vs baseline: 1.1923x; 1.1923x over previous
//
#include <hip/hip_runtime.h>
#include <hip/hip_bf16.h>

#define BB  8
#define CC  128
#define LXX 4096
#define LYY 1024
#define HH  4
#define DHH 32

typedef __attribute__((ext_vector_type(8))) short bf16x8;
typedef __attribute__((ext_vector_type(4))) float f32x4;

static __device__ __forceinline__ unsigned short f2bf(float f) {
    __hip_bfloat16 h = __float2bfloat16(f);
    return *reinterpret_cast<unsigned short*>(&h);
}

static __device__ __forceinline__ bf16x8 pack8(const float* f) {
    bf16x8 r;
#pragma unroll
    for (int i = 0; i < 8; ++i) {
        __hip_bfloat16 h = __float2bfloat16(f[i]);
        r[i] = *reinterpret_cast<short*>(&h);
    }
    return r;
}

// ================= merged MFMA projection (+fused conv for x) =================
__global__ __launch_bounds__(256) void proj_all_kernel(
    const float* __restrict__ x, const float* __restrict__ y,
    const float* __restrict__ ipw, const float* __restrict__ ipb,
    const float* __restrict__ c1w, const float* __restrict__ c1b,
    const float* __restrict__ c2w, const float* __restrict__ c2b,
    unsigned short* __restrict__ Qb, unsigned short* __restrict__ Kb,
    float* __restrict__ localS, float qscale)
{
    int tid  = threadIdx.x;
    int wv   = tid >> 6;
    int lane = tid & 63;
    int n16  = lane & 15;
    int quad = lane >> 4;

    int blk = blockIdx.x;
    bool isX = (blk < 512);
    const float* src; const float* wrow; const float* bias;
    unsigned short* dst; int L, bi, l0; float scale;
    if (isX) {
        bi = blk >> 6; l0 = (blk & 63) * 64;
        src = x + (size_t)bi * CC * LXX; L = LXX;
        wrow = ipw; bias = ipb; dst = Qb; scale = qscale;
    } else {
        int b2 = blk - 512;
        bi = b2 >> 4; l0 = (b2 & 15) * 64;
        src = y + (size_t)bi * CC * LYY; L = LYY;
        wrow = ipw + CC * CC; bias = ipb + CC; dst = Kb; scale = 1.0f;
    }
    int lw = l0 + wv * 16;
    int myl = lw + n16;

    bf16x8 bfr[4];
#pragma unroll
    for (int kk = 0; kk < 4; ++kk) {
        float t[8];
        const float* p = src + (size_t)(kk * 32 + quad * 8) * L + myl;
#pragma unroll
        for (int j = 0; j < 8; ++j) t[j] = p[(size_t)j * L];
        bfr[kk] = pack8(t);
    }

    const f32x4 fzero = {0.f, 0.f, 0.f, 0.f};

#pragma unroll 1
    for (int m = 0; m < 8; ++m) {
        int mc = m * 16;
        f32x4 acc = fzero;
#pragma unroll
        for (int kk = 0; kk < 4; ++kk) {
            const float* wp = wrow + (size_t)(mc + n16) * CC + kk * 32 + quad * 8;
            float t[8];
            *(float4*)(t) = *(const float4*)(wp);
            *(float4*)(t + 4) = *(const float4*)(wp + 4);
            bf16x8 afr = pack8(t);
            acc = __builtin_amdgcn_mfma_f32_16x16x32_bf16(afr, bfr[kk], acc, 0, 0, 0);
        }
        int h = mc >> 5, d0 = (mc & 31) + quad * 4;
        ushort4 u;
        float4 bq = *(const float4*)(bias + mc + quad * 4);
        u.x = f2bf((acc[0] + bq.x) * scale);
        u.y = f2bf((acc[1] + bq.y) * scale);
        u.z = f2bf((acc[2] + bq.z) * scale);
        u.w = f2bf((acc[3] + bq.w) * scale);
        *(ushort4*)(dst + (((size_t)(bi * HH + h) * L) + myl) * DHH + d0) = u;
    }

    if (isX) {
        float p = 0.f;
#pragma unroll
        for (int m2 = 0; m2 < 2; ++m2) {
            f32x4 hacc = fzero;
#pragma unroll
            for (int kk = 0; kk < 4; ++kk) {
                const float* wp = c1w + (size_t)(m2 * 16 + n16) * CC + kk * 32 + quad * 8;
                float t[8];
                *(float4*)(t) = *(const float4*)(wp);
                *(float4*)(t + 4) = *(const float4*)(wp + 4);
                bf16x8 afr = pack8(t);
                hacc = __builtin_amdgcn_mfma_f32_16x16x32_bf16(afr, bfr[kk], hacc, 0, 0, 0);
            }
#pragma unroll
            for (int r = 0; r < 4; ++r) {
                int o = m2 * 16 + quad * 4 + r;
                p = fmaf(c2w[o], fmaxf(hacc[r] + c1b[o], 0.0f), p);
            }
        }
        p += __shfl_xor(p, 16, 64);
        p += __shfl_xor(p, 32, 64);
        if (quad == 0) {
            float s = p + c2b[0];
            localS[(size_t)bi * LXX + myl] = 1.0f / (1.0f + __expf(-s));
        }
    }
}

// ================= fused attention (R8 structure — measured optimum) =================
// grid (LX/32, B), 256 thr = 4 waves; wave w owns key quarter [w*256, +256).
// Two-phase block-local softmax: phase 1 den accumulate + 1 barrier combine;
// phase 2 re-score with MFMA C-init = -log2(den) so f(k)=sum_h exp2(s+c_h),
// running key-max, 1 barrier, gating blend. ~124 live regs = the measured
// sweet spot: tighter caps spill (R11), smaller tiles serialize (R9).
__global__ __launch_bounds__(256, 4) void attn_fused_kernel(
    const unsigned short* __restrict__ Qh, const unsigned short* __restrict__ Kh,
    const float* __restrict__ localS,
    const float* __restrict__ gw, const float* __restrict__ gb,
    float* __restrict__ out)
{
    int tid = threadIdx.x;
    int w = tid >> 6;           // key quarter 0..3
    int lane = tid & 63;
    int n16 = lane & 15;
    int quad = lane >> 4;
    int bi = blockIdx.y;
    int q0 = blockIdx.x * 32;

    __shared__ float dlds[4][2][HH][16];   // [w][qt][h][row]
    __shared__ float mlds[4][2][16];       // [w][qt][row]

    bf16x8 afr[2][HH];
#pragma unroll
    for (int qt = 0; qt < 2; ++qt)
#pragma unroll
        for (int h = 0; h < HH; ++h)
            afr[qt][h] = *(const bf16x8*)(Qh +
                (((size_t)bi * HH + h) * LXX + q0 + qt * 16 + n16) * DHH + quad * 8);

    const unsigned short* Kbase = Kh + (((size_t)bi * HH) * LYY + w * 256 + n16) * DHH + quad * 8;

    const f32x4 fzero = {0.f, 0.f, 0.f, 0.f};

    // ---- phase 1: denominators over this wave's 256 keys ----
    f32x4 den[2][HH];
#pragma unroll
    for (int qt = 0; qt < 2; ++qt)
#pragma unroll
        for (int h = 0; h < HH; ++h) den[qt][h] = fzero;

#pragma unroll 2
    for (int t = 0; t < 16; ++t) {
        bf16x8 bfr[HH];
#pragma unroll
        for (int h = 0; h < HH; ++h)
            bfr[h] = *(const bf16x8*)(Kbase + ((size_t)h * LYY + t * 16) * DHH);
#pragma unroll
        for (int h = 0; h < HH; ++h) {
            f32x4 s0 = __builtin_amdgcn_mfma_f32_16x16x32_bf16(afr[0][h], bfr[h], fzero, 0, 0, 0);
            f32x4 s1 = __builtin_amdgcn_mfma_f32_16x16x32_bf16(afr[1][h], bfr[h], fzero, 0, 0, 0);
#pragma unroll
            for (int r = 0; r < 4; ++r) {
                den[0][h][r] += __builtin_amdgcn_exp2f(s0[r]);
                den[1][h][r] += __builtin_amdgcn_exp2f(s1[r]);
            }
        }
    }
#pragma unroll
    for (int off = 1; off < 16; off <<= 1)
#pragma unroll
        for (int qt = 0; qt < 2; ++qt)
#pragma unroll
            for (int h = 0; h < HH; ++h)
#pragma unroll
                for (int r = 0; r < 4; ++r)
                    den[qt][h][r] += __shfl_xor(den[qt][h][r], off, 64);
    if (n16 == 0) {
#pragma unroll
        for (int qt = 0; qt < 2; ++qt)
#pragma unroll
            for (int h = 0; h < HH; ++h)
#pragma unroll
                for (int r = 0; r < 4; ++r) dlds[w][qt][h][quad * 4 + r] = den[qt][h][r];
    }
    __syncthreads();

    // c = -log2(total den); broadcast LDS reads (same addr within quad -> no conflict)
    f32x4 cc[2][HH];
#pragma unroll
    for (int qt = 0; qt < 2; ++qt)
#pragma unroll
        for (int h = 0; h < HH; ++h)
#pragma unroll
            for (int r = 0; r < 4; ++r) {
                int row = quad * 4 + r;
                float d = dlds[0][qt][h][row] + dlds[1][qt][h][row] +
                          dlds[2][qt][h][row] + dlds[3][qt][h][row];
                cc[qt][h][r] = -__builtin_amdgcn_logf(d);
            }

    // ---- phase 2: f(k) = sum_h exp2(s + c_h); running max over keys ----
    f32x4 vm0 = fzero, vm1 = fzero;    // f(k) > 0, so 0 is a valid -inf
#pragma unroll 2
    for (int t = 0; t < 16; ++t) {
        bf16x8 bfr[HH];
#pragma unroll
        for (int h = 0; h < HH; ++h)
            bfr[h] = *(const bf16x8*)(Kbase + ((size_t)h * LYY + t * 16) * DHH);
        f32x4 f0 = fzero, f1 = fzero;
#pragma unroll
        for (int h = 0; h < HH; ++h) {
            f32x4 s0 = __builtin_amdgcn_mfma_f32_16x16x32_bf16(afr[0][h], bfr[h], cc[0][h], 0, 0, 0);
            f32x4 s1 = __builtin_amdgcn_mfma_f32_16x16x32_bf16(afr[1][h], bfr[h], cc[1][h], 0, 0, 0);
#pragma unroll
            for (int r = 0; r < 4; ++r) {
                f0[r] += __builtin_amdgcn_exp2f(s0[r]);
                f1[r] += __builtin_amdgcn_exp2f(s1[r]);
            }
        }
#pragma unroll
        for (int r = 0; r < 4; ++r) {
            vm0[r] = fmaxf(vm0[r], f0[r]);
            vm1[r] = fmaxf(vm1[r], f1[r]);
        }
    }
#pragma unroll
    for (int off = 1; off < 16; off <<= 1)
#pragma unroll
        for (int r = 0; r < 4; ++r) {
            vm0[r] = fmaxf(vm0[r], __shfl_xor(vm0[r], off, 64));
            vm1[r] = fmaxf(vm1[r], __shfl_xor(vm1[r], off, 64));
        }
    if (n16 == 0) {
#pragma unroll
        for (int r = 0; r < 4; ++r) {
            mlds[w][0][quad * 4 + r] = vm0[r];
            mlds[w][1][quad * 4 + r] = vm1[r];
        }
    }
    __syncthreads();
    if (tid < 32) {
        int qq = tid >> 4;
        int row = tid & 15;
        float m = fmaxf(fmaxf(mlds[0][qq][row], mlds[1][qq][row]),
                        fmaxf(mlds[2][qq][row], mlds[3][qq][row]));
        float cs = 0.25f * m;
        int orow = q0 + qq * 16 + row;
        float ls = localS[(size_t)bi * LXX + orow];
        float z = gw[0] * cs + gw[1] * ls + gb[0];
        float alpha = 1.0f / (1.0f + __expf(-z));
        out[(size_t)bi * LXX + orow] = alpha * cs + (1.0f - alpha) * ls;
    }
}

extern "C" void kernel_launch(void* const* d_in, const int* in_sizes, int n_in,
                              void* d_out, int out_size, void* d_ws, size_t ws_size,
                              hipStream_t stream) {
    const float* x   = (const float*)d_in[0];
    const float* y   = (const float*)d_in[1];
    const float* ipw = (const float*)d_in[2];
    const float* ipb = (const float*)d_in[3];
    const float* c1w = (const float*)d_in[4];
    const float* c1b = (const float*)d_in[5];
    const float* c2w = (const float*)d_in[6];
    const float* c2b = (const float*)d_in[7];
    const float* gw  = (const float*)d_in[8];
    const float* gb  = (const float*)d_in[9];
    float* out = (float*)d_out;

    float* localS = (float*)d_ws;                                // 32768 f32
    unsigned short* Qb = (unsigned short*)(localS + 32768);      // B*H*LX*DH bf16
    unsigned short* Kb = Qb + (size_t)BB * HH * LXX * DHH;       // B*H*LY*DH bf16

    // 1/sqrt(32) * log2(e): exp2-domain softmax, folded into Q only
    const float qscale = 0.17677669529663687f * 1.4426950408889634f;

    hipLaunchKernelGGL(proj_all_kernel, dim3(640), dim3(256), 0, stream,
                       x, y, ipw, ipb, c1w, c1b, c2w, c2b, Qb, Kb, localS, qscale);
    hipLaunchKernelGGL(attn_fused_kernel, dim3(LXX / 32, BB), dim3(256), 0, stream,
                       Qb, Kb, localS, gw, gb, out);
}